// Round 2
// baseline (1324.207 us; speedup 1.0000x reference)
//
#include <hip/hip_runtime.h>

#define NB 4
#define NC 64
#define NC2 32
#define NH 60
#define NW 60
#define NPIX (NH*NW)         // 3600
#define HP 66                // embed padded (pad 3)
#define MP 62                // match padded (pad 1)
#define HR 20
#define RP 22                // ref padded (pad 1)
#define NL 400
#define OHW 180

// workspace layout (floats)
#define SZ_E   (NB*HP*HP*NC)        // 1,115,136  E_t [b][row][col][c]
#define SZ_XP  (NB*NC2*MP*MP)       // 492,032    [b][c][62][62]
#define SZ_RP  (NB*NC2*RP*RP)       // 61,952     [b][c][22][22]
#define SZ_IN  (NB*NL)              // 1,600
#define SZ_Y   (NB*NPIX*NL)         // 5,760,000  y_t [b][h][w][l]

// embed conv1x1 + prelu -> padded, channel-fastest layout
__global__ __launch_bounds__(256) void k_conv_embed(
    const float* __restrict__ x, const float* __restrict__ Wa,
    const float* __restrict__ ba, const float* __restrict__ aa,
    float* __restrict__ E_t) {
  __shared__ float Ws[64*64];   // transposed: Ws[c][co]
  __shared__ float bs[64];
  __shared__ float al;
  int t = threadIdx.x;
  for (int i = t; i < 64*64; i += 256) {
    int co = i >> 6, c = i & 63;
    Ws[c*64 + co] = Wa[i];
  }
  if (t < 64) bs[t] = ba[t];
  if (t == 0) al = aa[0];
  __syncthreads();
  int lane = t & 63, wid = t >> 6;
  int pix = blockIdx.x * 4 + wid;       // grid.x=900 -> pix<3600 always
  int b = blockIdx.y;
  int ph = pix / NW, pw = pix % NW;
  const float* xb = x + b*NC*NPIX + pix;
  float acc = bs[lane];
  #pragma unroll 8
  for (int c = 0; c < 64; ++c)
    acc = fmaf(xb[c*NPIX], Ws[c*64 + lane], acc);
  acc = acc >= 0.f ? acc : al*acc;
  E_t[((b*HP + ph+3)*HP + (pw+3))*NC + lane] = acc;
}

// match conv1x1 + prelu -> padded [b][c2][62][62]
__global__ __launch_bounds__(256) void k_conv_match(
    const float* __restrict__ x, const float* __restrict__ Wm,
    const float* __restrict__ bm, const float* __restrict__ am,
    float* __restrict__ xp) {
  int idx = blockIdx.x*256 + threadIdx.x;
  if (idx >= NB*NC2*NPIX) return;
  int pix = idx % NPIX; int tmp = idx / NPIX;
  int co = tmp % NC2; int b = tmp / NC2;
  float alpha = am[0];
  const float* xb = x + b*NC*NPIX + pix;
  const float* wr = Wm + co*64;
  float acc = bm[co];
  #pragma unroll 8
  for (int c = 0; c < 64; ++c)
    acc = fmaf(xb[c*NPIX], wr[c], acc);
  acc = acc >= 0.f ? acc : alpha*acc;
  int ph = pix / NW, pw = pix % NW;
  xp[((b*NC2 + co)*MP + ph+1)*MP + (pw+1)] = acc;
}

// bilinear down (exact subsample at 3h+1) + conv1x1 + prelu -> padded [b][c2][22][22]
__global__ __launch_bounds__(256) void k_conv_ref(
    const float* __restrict__ x, const float* __restrict__ Wm,
    const float* __restrict__ bm, const float* __restrict__ am,
    float* __restrict__ refp) {
  int idx = blockIdx.x*256 + threadIdx.x;
  if (idx >= NB*NC2*HR*HR) return;
  int pos = idx % (HR*HR); int tmp = idx / (HR*HR);
  int co = tmp % NC2; int b = tmp / NC2;
  int hr = pos / HR, wr_ = pos % HR;
  float alpha = am[0];
  const float* xb = x + b*NC*NPIX + (3*hr+1)*NW + (3*wr_+1);
  const float* wrow = Wm + co*64;
  float acc = bm[co];
  #pragma unroll 8
  for (int c = 0; c < 64; ++c)
    acc = fmaf(xb[c*NPIX], wrow[c], acc);
  acc = acc >= 0.f ? acc : alpha*acc;
  refp[((b*NC2 + co)*RP + hr+1)*RP + (wr_+1)] = acc;
}

// per-(b,l) patch inverse norm
__global__ __launch_bounds__(64) void k_invn(
    const float* __restrict__ refp, float* __restrict__ invn) {
  int bl = blockIdx.x;
  int b = bl / NL, l = bl % NL;
  int lh = l / HR, lw = l % HR;
  int t = threadIdx.x;
  float ss = 0.f;
  for (int e = t; e < NC2*9; e += 64) {
    int c = e / 9, r = e % 9;
    int i = r / 3, j = r % 3;
    float v = refp[((b*NC2 + c)*RP + lh+i)*RP + (lw+j)];
    ss = fmaf(v, v, ss);
  }
  #pragma unroll
  for (int off = 32; off > 0; off >>= 1)
    ss += __shfl_xor(ss, off);
  if (t == 0) invn[bl] = 1.f / fmaxf(sqrtf(ss), 1e-4f);
}

// correlation: y_t[b][h][w][l] = sum_{c,i,j} xp[b,c,h+i,w+j]*refp[b,c,lh+i,lw+j]
// (invn applied later in softmax). grid (8,8,4), block 256.
__global__ __launch_bounds__(256) void k_corr(
    const float* __restrict__ xp, const float* __restrict__ refp,
    float* __restrict__ y_t) {
  __shared__ float rs_[16*RP*RP];   // 7744 floats
  __shared__ float xs_[16*10*10];   // 1600 floats
  int t = threadIdx.x;
  int b = blockIdx.z;
  int px0 = blockIdx.x*8, py0 = blockIdx.y*8;
  int pos = t & 63, lq = t >> 6;    // wave id = l-quarter (uniform per wave)
  int py = pos >> 3, px = pos & 7;
  int h = py0 + py, w = px0 + px;
  bool valid = (h < NH) && (w < NW);
  float* yo = y_t + ((size_t)(b*NPIX + (valid ? h*NW + w : 0)))*NL;
  for (int cc = 0; cc < 2; ++cc) {
    int cbase = cc*16;
    __syncthreads();
    for (int i = t; i < 16*RP*RP; i += 256)
      rs_[i] = refp[(b*NC2 + cbase)*(RP*RP) + i];
    for (int i = t; i < 1600; i += 256) {
      int c = i / 100, r = i % 100;
      int dy = r / 10, dx = r % 10;
      int yy = py0 + dy, xx = px0 + dx;
      float v = 0.f;
      if (yy < MP && xx < MP)
        v = xp[((b*NC2 + cbase + c)*MP + yy)*MP + xx];
      xs_[i] = v;
    }
    __syncthreads();
    for (int g = 0; g < 25; ++g) {
      int l0 = lq*100 + g*4;           // l0..l0+3 share lh (lw0<=16)
      int lh = l0 / HR, lw = l0 % HR;
      float a0=0.f, a1=0.f, a2=0.f, a3=0.f;
      for (int c = 0; c < 16; ++c) {
        const float* xr = &xs_[c*100 + py*10 + px];
        const float* rr = &rs_[c*(RP*RP) + lh*RP + lw];
        #pragma unroll
        for (int i = 0; i < 3; ++i) {
          #pragma unroll
          for (int j = 0; j < 3; ++j) {
            float xv = xr[i*10 + j];
            const float* rp = &rr[i*RP + j];
            a0 = fmaf(xv, rp[0], a0);
            a1 = fmaf(xv, rp[1], a1);
            a2 = fmaf(xv, rp[2], a2);
            a3 = fmaf(xv, rp[3], a3);
          }
        }
      }
      if (valid) {
        float* yp = yo + l0;
        if (cc == 0) { yp[0]=a0; yp[1]=a1; yp[2]=a2; yp[3]=a3; }
        else         { yp[0]+=a0; yp[1]+=a1; yp[2]+=a2; yp[3]+=a3; }
      }
    }
  }
}

// softmax over L per (b,h,w); applies 10*invn[b,l] first. One wave per position.
__global__ __launch_bounds__(256) void k_softmax(
    float* __restrict__ y_t, const float* __restrict__ invn) {
  int t = threadIdx.x;
  int lane = t & 63, wid = t >> 6;
  int gpos = blockIdx.x*4 + wid;
  int b = gpos / NPIX, rem = gpos % NPIX;
  float* yp = y_t + ((size_t)(b*NPIX + rem))*NL;
  const float* inv = invn + b*NL;
  float vals[7];
  float m = -1e30f;
  #pragma unroll
  for (int k = 0; k < 7; ++k) {
    int l = lane + 64*k;
    float v = -1e30f;
    if (l < NL) v = yp[l] * inv[l] * 10.0f;
    vals[k] = v;
    m = fmaxf(m, v);
  }
  #pragma unroll
  for (int off = 32; off > 0; off >>= 1)
    m = fmaxf(m, __shfl_xor(m, off));
  float s = 0.f;
  #pragma unroll
  for (int k = 0; k < 7; ++k) {
    float e = expf(vals[k] - m);   // invalid lanes: exp(-huge)=0
    vals[k] = e;
    s += e;
  }
  #pragma unroll
  for (int off = 32; off > 0; off >>= 1)
    s += __shfl_xor(s, off);
  float r = 1.f / s;
  #pragma unroll
  for (int k = 0; k < 7; ++k) {
    int l = lane + 64*k;
    if (l < NL) yp[l] = vals[k] * r;
  }
}

// transpose-conv: out[b,c,3h0+r,3w0+s] = (1/6) sum_{dh,dw,l} y[b,l,h0+1-dh,w0+1-dw]
//                                           * E[b,c,3(lh+dh)+r,3(lw+dw)+s]
// block per (b,h0,w0); wave=s, lane=c, 3 accumulators r=0..2.
__global__ __launch_bounds__(192) void k_tconv(
    const float* __restrict__ y_t, const float* __restrict__ E_t,
    float* __restrict__ out) {
  __shared__ float ybp[9*24*24];   // zero-padded y window: [slot][lh+2][lw+2]
  int t = threadIdx.x;
  int lane = t & 63;
  int s = t >> 6;                  // 0..2
  int h0 = blockIdx.x, w0 = blockIdx.y, b = blockIdx.z;
  for (int i = t; i < 9*576; i += 192) ybp[i] = 0.f;
  __syncthreads();
  for (int i = t; i < 9*NL; i += 192) {
    int sl = i / NL, l = i % NL;
    int dh = sl/3 - 1, dw = sl%3 - 1;
    int hh = h0 + dh, ww = w0 + dw;
    float v = 0.f;
    if (hh >= 0 && hh < NH && ww >= 0 && ww < NW)
      v = y_t[((size_t)(b*NPIX + hh*NW + ww))*NL + l];
    int lh = l / HR, lw = l % HR;
    ybp[sl*576 + (lh+2)*24 + (lw+2)] = v;
  }
  __syncthreads();
  float a0=0.f, a1=0.f, a2=0.f;
  const float* Eb0 = E_t + ((size_t)(b*HP)*HP + s)*NC + lane;  // row 0, col s
  for (int u = 0; u < 22; ++u) {
    const float* Er = Eb0 + (size_t)(3*u)*HP*NC;
    const float* qb = &ybp[u*24];
    for (int v = 0; v < 22; ++v) {
      float E0 = Er[v*3*NC];                 // row 3u,   col 3v+s
      float E1 = Er[HP*NC + v*3*NC];         // row 3u+1
      float E2 = Er[2*HP*NC + v*3*NC];       // row 3u+2
      const float* q = qb + v;
      #pragma unroll
      for (int dh = 0; dh < 3; ++dh) {
        #pragma unroll
        for (int dw = 0; dw < 3; ++dw) {
          // ybp[slot(dh,dw)][u-dh+2][v-dw+2]; zeros cover invalid lh/lw
          float yv = q[((2-dh)*3 + (2-dw))*576 + (2-dh)*24 + (2-dw)];
          a0 = fmaf(yv, E0, a0);
          a1 = fmaf(yv, E1, a1);
          a2 = fmaf(yv, E2, a2);
        }
      }
    }
  }
  const float sc = 1.f/6.f;
  float* ob = out + ((size_t)(b*NC + lane)*OHW + 3*h0)*OHW + 3*w0 + s;
  ob[0]     = a0*sc;
  ob[OHW]   = a1*sc;
  ob[2*OHW] = a2*sc;
}

extern "C" void kernel_launch(void* const* d_in, const int* in_sizes, int n_in,
                              void* d_out, int out_size, void* d_ws, size_t ws_size,
                              hipStream_t stream) {
  (void)in_sizes; (void)n_in; (void)out_size; (void)ws_size;
  const float* x   = (const float*)d_in[0];
  const float* Wa  = (const float*)d_in[1];
  const float* ba  = (const float*)d_in[2];
  const float* aa  = (const float*)d_in[3];
  const float* Wm1 = (const float*)d_in[4];
  const float* bm1 = (const float*)d_in[5];
  const float* am1 = (const float*)d_in[6];
  const float* Wm2 = (const float*)d_in[7];
  const float* bm2 = (const float*)d_in[8];
  const float* am2 = (const float*)d_in[9];
  float* out = (float*)d_out;

  float* E_t  = (float*)d_ws;
  float* xp   = E_t + SZ_E;
  float* refp = xp + SZ_XP;
  float* invn = refp + SZ_RP;
  float* y_t  = invn + SZ_IN;

  // zero the padded buffers (ws is re-poisoned before every launch)
  hipMemsetAsync(d_ws, 0, (size_t)(SZ_E + SZ_XP + SZ_RP)*sizeof(float), stream);

  k_conv_embed<<<dim3(900, NB), 256, 0, stream>>>(x, Wa, ba, aa, E_t);
  k_conv_match<<<(NB*NC2*NPIX)/256, 256, 0, stream>>>(x, Wm1, bm1, am1, xp);
  k_conv_ref<<<(NB*NC2*HR*HR)/256, 256, 0, stream>>>(x, Wm2, bm2, am2, refp);
  k_invn<<<NB*NL, 64, 0, stream>>>(refp, invn);
  k_corr<<<dim3(8, 8, NB), 256, 0, stream>>>(xp, refp, y_t);
  k_softmax<<<(NB*NPIX)/4, 256, 0, stream>>>(y_t, invn);
  k_tconv<<<dim3(NH, NW, NB), 192, 0, stream>>>(y_t, E_t, out);
}

// Round 3
// 383.913 us; speedup vs baseline: 3.4492x; 3.4492x over previous
//
#include <hip/hip_runtime.h>
#include <hip/hip_bf16.h>

typedef __hip_bfloat16 bf16_t;
using f32x4  = __attribute__((ext_vector_type(4))) float;
using bf16x8 = __attribute__((ext_vector_type(8))) short;

#define NB 4
#define NC 64
#define NC2 32
#define NH 60
#define NW 60
#define NPIX (NH*NW)         // 3600
#define HP 66                // embed padded (pad 3)
#define MP 62                // match padded (pad 1)
#define HR 20
#define RP 22                // ref padded (pad 1)
#define NL 400
#define OHW 180
#define KPAD 512             // 484 real k=(u,v), padded

// workspace layout (floats)
#define SZ_E   (NB*HP*HP*NC)        // 1,115,136  E_t [b][row][col][c]
#define SZ_XP  (NB*NC2*MP*MP)       // 492,032    [b][c][62][62]
#define SZ_RP  (NB*NC2*RP*RP)       // 61,952     [b][c][22][22]
#define SZ_IN  (NB*NL)              // 1,600
#define SZ_Y   (NB*NPIX*NL)         // 5,760,000  y_t [b][h][w][l]
// then bf16: ApSwz 4*45*16*5*512 = 7,372,800 ; EbSwz 4*12*16*3*512 = 1,179,648

// embed conv1x1 + prelu -> padded, channel-fastest layout
__global__ __launch_bounds__(256) void k_conv_embed(
    const float* __restrict__ x, const float* __restrict__ Wa,
    const float* __restrict__ ba, const float* __restrict__ aa,
    float* __restrict__ E_t) {
  __shared__ float Ws[64*64];
  __shared__ float bs[64];
  __shared__ float al;
  int t = threadIdx.x;
  for (int i = t; i < 64*64; i += 256) {
    int co = i >> 6, c = i & 63;
    Ws[c*64 + co] = Wa[i];
  }
  if (t < 64) bs[t] = ba[t];
  if (t == 0) al = aa[0];
  __syncthreads();
  int lane = t & 63, wid = t >> 6;
  int pix = blockIdx.x * 4 + wid;
  int b = blockIdx.y;
  int ph = pix / NW, pw = pix % NW;
  const float* xb = x + b*NC*NPIX + pix;
  float acc = bs[lane];
  #pragma unroll 8
  for (int c = 0; c < 64; ++c)
    acc = fmaf(xb[c*NPIX], Ws[c*64 + lane], acc);
  acc = acc >= 0.f ? acc : al*acc;
  E_t[((b*HP + ph+3)*HP + (pw+3))*NC + lane] = acc;
}

// match conv1x1 + prelu -> padded [b][c2][62][62]
__global__ __launch_bounds__(256) void k_conv_match(
    const float* __restrict__ x, const float* __restrict__ Wm,
    const float* __restrict__ bm, const float* __restrict__ am,
    float* __restrict__ xp) {
  int idx = blockIdx.x*256 + threadIdx.x;
  if (idx >= NB*NC2*NPIX) return;
  int pix = idx % NPIX; int tmp = idx / NPIX;
  int co = tmp % NC2; int b = tmp / NC2;
  float alpha = am[0];
  const float* xb = x + b*NC*NPIX + pix;
  const float* wr = Wm + co*64;
  float acc = bm[co];
  #pragma unroll 8
  for (int c = 0; c < 64; ++c)
    acc = fmaf(xb[c*NPIX], wr[c], acc);
  acc = acc >= 0.f ? acc : alpha*acc;
  int ph = pix / NW, pw = pix % NW;
  xp[((b*NC2 + co)*MP + ph+1)*MP + (pw+1)] = acc;
}

// bilinear down (exact subsample at 3h+1) + conv1x1 + prelu -> padded [b][c2][22][22]
__global__ __launch_bounds__(256) void k_conv_ref(
    const float* __restrict__ x, const float* __restrict__ Wm,
    const float* __restrict__ bm, const float* __restrict__ am,
    float* __restrict__ refp) {
  int idx = blockIdx.x*256 + threadIdx.x;
  if (idx >= NB*NC2*HR*HR) return;
  int pos = idx % (HR*HR); int tmp = idx / (HR*HR);
  int co = tmp % NC2; int b = tmp / NC2;
  int hr = pos / HR, wr_ = pos % HR;
  float alpha = am[0];
  const float* xb = x + b*NC*NPIX + (3*hr+1)*NW + (3*wr_+1);
  const float* wrow = Wm + co*64;
  float acc = bm[co];
  #pragma unroll 8
  for (int c = 0; c < 64; ++c)
    acc = fmaf(xb[c*NPIX], wrow[c], acc);
  acc = acc >= 0.f ? acc : alpha*acc;
  refp[((b*NC2 + co)*RP + hr+1)*RP + (wr_+1)] = acc;
}

// per-(b,l) patch inverse norm
__global__ __launch_bounds__(64) void k_invn(
    const float* __restrict__ refp, float* __restrict__ invn) {
  int bl = blockIdx.x;
  int b = bl / NL, l = bl % NL;
  int lh = l / HR, lw = l % HR;
  int t = threadIdx.x;
  float ss = 0.f;
  for (int e = t; e < NC2*9; e += 64) {
    int c = e / 9, r = e % 9;
    int i = r / 3, j = r % 3;
    float v = refp[((b*NC2 + c)*RP + lh+i)*RP + (lw+j)];
    ss = fmaf(v, v, ss);
  }
  #pragma unroll
  for (int off = 32; off > 0; off >>= 1)
    ss += __shfl_xor(ss, off);
  if (t == 0) invn[bl] = 1.f / fmaxf(sqrtf(ss), 1e-4f);
}

// correlation: y_t[b][h][w][l]
__global__ __launch_bounds__(256) void k_corr(
    const float* __restrict__ xp, const float* __restrict__ refp,
    float* __restrict__ y_t) {
  __shared__ float rs_[16*RP*RP];
  __shared__ float xs_[16*10*10];
  int t = threadIdx.x;
  int b = blockIdx.z;
  int px0 = blockIdx.x*8, py0 = blockIdx.y*8;
  int pos = t & 63, lq = t >> 6;
  int py = pos >> 3, px = pos & 7;
  int h = py0 + py, w = px0 + px;
  bool valid = (h < NH) && (w < NW);
  float* yo = y_t + ((size_t)(b*NPIX + (valid ? h*NW + w : 0)))*NL;
  for (int cc = 0; cc < 2; ++cc) {
    int cbase = cc*16;
    __syncthreads();
    for (int i = t; i < 16*RP*RP; i += 256)
      rs_[i] = refp[(b*NC2 + cbase)*(RP*RP) + i];
    for (int i = t; i < 1600; i += 256) {
      int c = i / 100, r = i % 100;
      int dy = r / 10, dx = r % 10;
      int yy = py0 + dy, xx = px0 + dx;
      float v = 0.f;
      if (yy < MP && xx < MP)
        v = xp[((b*NC2 + cbase + c)*MP + yy)*MP + xx];
      xs_[i] = v;
    }
    __syncthreads();
    for (int g = 0; g < 25; ++g) {
      int l0 = lq*100 + g*4;
      int lh = l0 / HR, lw = l0 % HR;
      float a0=0.f, a1=0.f, a2=0.f, a3=0.f;
      for (int c = 0; c < 16; ++c) {
        const float* xr = &xs_[c*100 + py*10 + px];
        const float* rr = &rs_[c*(RP*RP) + lh*RP + lw];
        #pragma unroll
        for (int i = 0; i < 3; ++i) {
          #pragma unroll
          for (int j = 0; j < 3; ++j) {
            float xv = xr[i*10 + j];
            const float* rp = &rr[i*RP + j];
            a0 = fmaf(xv, rp[0], a0);
            a1 = fmaf(xv, rp[1], a1);
            a2 = fmaf(xv, rp[2], a2);
            a3 = fmaf(xv, rp[3], a3);
          }
        }
      }
      if (valid) {
        float* yp = yo + l0;
        if (cc == 0) { yp[0]=a0; yp[1]=a1; yp[2]=a2; yp[3]=a3; }
        else         { yp[0]+=a0; yp[1]+=a1; yp[2]+=a2; yp[3]+=a3; }
      }
    }
  }
}

// softmax over L per (b,h,w); applies 10*invn[b,l] first.
__global__ __launch_bounds__(256) void k_softmax(
    float* __restrict__ y_t, const float* __restrict__ invn) {
  int t = threadIdx.x;
  int lane = t & 63, wid = t >> 6;
  int gpos = blockIdx.x*4 + wid;
  int b = gpos / NPIX, rem = gpos % NPIX;
  float* yp = y_t + ((size_t)(b*NPIX + rem))*NL;
  const float* inv = invn + b*NL;
  float vals[7];
  float m = -1e30f;
  #pragma unroll
  for (int k = 0; k < 7; ++k) {
    int l = lane + 64*k;
    float v = -1e30f;
    if (l < NL) v = yp[l] * inv[l] * 10.0f;
    vals[k] = v;
    m = fmaxf(m, v);
  }
  #pragma unroll
  for (int off = 32; off > 0; off >>= 1)
    m = fmaxf(m, __shfl_xor(m, off));
  float s = 0.f;
  #pragma unroll
  for (int k = 0; k < 7; ++k) {
    float e = expf(vals[k] - m);
    vals[k] = e;
    s += e;
  }
  #pragma unroll
  for (int off = 32; off > 0; off >>= 1)
    s += __shfl_xor(s, off);
  float r = 1.f / s;
  #pragma unroll
  for (int k = 0; k < 7; ++k) {
    int l = lane + 64*k;
    if (l < NL) yp[l] = vals[k] * r;
  }
}

// A'[b][m=(h0,w0)][k=(u,v)] = sum_{dh,dw} y[b,(u-dh,v-dw),h0+1-dh,w0+1-dw]
// written bf16 in MFMA-fragment-swizzled order:
// idx = ((((b*45+m/80)*16+k/32)*5+(m%80)/16)*64 + ((k>>3)&3)*16 + (m&15))*8 + (k&7)
__global__ __launch_bounds__(256) void k_aprime(
    const float* __restrict__ y_t, bf16_t* __restrict__ Ap) {
  __shared__ float ys[36*NL];   // 57.6 KB: [i][jj][l], i,jj in [0,6)
  int t = threadIdx.x;
  int b = blockIdx.z;
  int h0base = blockIdx.y*4, w0base = blockIdx.x*4;
  for (int idx = t; idx < 36*NL; idx += 256) {
    int pos = idx / NL, l = idx % NL;
    int i = pos / 6, jj = pos % 6;
    int hh = h0base - 1 + i, ww = w0base - 1 + jj;
    float v = 0.f;
    if (hh >= 0 && hh < NH && ww >= 0 && ww < NW)
      v = y_t[((size_t)(b*NPIX + hh*NW + ww))*NL + l];
    ys[idx] = v;
  }
  __syncthreads();
  int row = t >> 4, klane = t & 15;
  int h0r = row >> 2, w0r = row & 3;
  int m = (h0base + h0r)*NW + (w0base + w0r);
  int pblk = m / 80, pf = (m % 80) >> 4, mrow = m & 15;
  size_t rowbase = ((size_t)(b*45 + pblk)*16);
  for (int kk = 0; kk < 32; ++kk) {
    int k = klane + kk*16;
    float acc = 0.f;
    if (k < 484) {
      int u = k / 22, v = k % 22;
      #pragma unroll
      for (int dh = 0; dh < 3; ++dh) {
        #pragma unroll
        for (int dw = 0; dw < 3; ++dw) {
          int lh = u - dh, lw = v - dw;
          if ((unsigned)lh < HR && (unsigned)lw < HR) {
            int i = h0r + 2 - dh, jj = w0r + 2 - dw;
            acc += ys[(i*6 + jj)*NL + lh*HR + lw];
          }
        }
      }
    }
    size_t idx = (((rowbase + (k>>5))*5 + pf)*64 + ((k>>3)&3)*16 + mrow)*8 + (k&7);
    Ap[idx] = __float2bfloat16(acc);
  }
}

// Eb[b][n=(c,rr,s)][k=(u,v)] = E_pad[b][c][3u+rr][3v+s], swizzled:
// idx = ((((b*12+n/48)*16+k/32)*3+(n%48)/16)*64 + ((k>>3)&3)*16 + (n&15))*8 + (k&7)
__global__ __launch_bounds__(256) void k_ebswz(
    const float* __restrict__ E_t, bf16_t* __restrict__ Eb) {
  int n = blockIdx.x, b = blockIdx.y;
  int c = n / 9, n9 = n % 9, rr = n9 / 3, s = n9 % 3;
  size_t nbase = ((size_t)(b*12 + n/48)*16);
  for (int k = threadIdx.x; k < KPAD; k += 256) {
    float v = 0.f;
    if (k < 484) {
      int u = k / 22, vv = k % 22;
      v = E_t[((size_t)((b*HP + 3*u + rr)*HP + 3*vv + s))*NC + c];
    }
    size_t idx = (((nbase + (k>>5))*3 + (n%48)/16)*64 + ((k>>3)&3)*16 + (n&15))*8 + (k&7);
    Eb[idx] = __float2bfloat16(v);
  }
}

// out[(c,rr,s)][(h0,w0)] = (1/6) sum_k Eb[n][k] * A'[m][k]
// D rows = Eb-rows (A-operand), D cols = positions (B-operand).
// 1 wave per block; wave tile 48 rows x 80 cols; K = 512 (16 steps of 32).
__global__ __launch_bounds__(64) void k_tgemm(
    const bf16x8* __restrict__ Eb, const bf16x8* __restrict__ Ap,
    float* __restrict__ out) {
  int L = threadIdx.x;
  int pb = blockIdx.x, rb = blockIdx.y, b = blockIdx.z;
  const bf16x8* pa = Eb + ((size_t)(b*12 + rb)*16)*3*64 + L;   // +ks*192 +rf*64
  const bf16x8* pp = Ap + ((size_t)(b*45 + pb)*16)*5*64 + L;   // +ks*320 +pf*64
  f32x4 acc[3][5];
  #pragma unroll
  for (int i = 0; i < 3; ++i)
    #pragma unroll
    for (int j = 0; j < 5; ++j)
      acc[i][j] = {0.f, 0.f, 0.f, 0.f};
  bf16x8 af[3], bf[5], afn[3], bfn[5];
  #pragma unroll
  for (int i = 0; i < 3; ++i) af[i] = pa[i*64];
  #pragma unroll
  for (int j = 0; j < 5; ++j) bf[j] = pp[j*64];
  for (int ks = 0; ks < 16; ++ks) {
    if (ks < 15) {
      const bf16x8* na = pa + (ks+1)*192;
      const bf16x8* nb = pp + (ks+1)*320;
      #pragma unroll
      for (int i = 0; i < 3; ++i) afn[i] = na[i*64];
      #pragma unroll
      for (int j = 0; j < 5; ++j) bfn[j] = nb[j*64];
    }
    #pragma unroll
    for (int i = 0; i < 3; ++i)
      #pragma unroll
      for (int j = 0; j < 5; ++j)
        acc[i][j] = __builtin_amdgcn_mfma_f32_16x16x32_bf16(af[i], bf[j], acc[i][j], 0, 0, 0);
    #pragma unroll
    for (int i = 0; i < 3; ++i) af[i] = afn[i];
    #pragma unroll
    for (int j = 0; j < 5; ++j) bf[j] = bfn[j];
  }
  // store: n = rb*48+rf*16+quad*4+r -> (c,rr,s); m = pb*80+pf*16+col -> (h0,w0)
  int quad = L >> 4, col = L & 15;
  const float sc = 1.f/6.f;
  #pragma unroll
  for (int pf = 0; pf < 5; ++pf) {
    int m = pb*80 + pf*16 + col;
    int h0 = m / 60, w0 = m % 60;
    int posoff = b*(NC*OHW*OHW) + h0*540 + w0*3;
    #pragma unroll
    for (int rf = 0; rf < 3; ++rf) {
      #pragma unroll
      for (int r = 0; r < 4; ++r) {
        int n = rb*48 + rf*16 + quad*4 + r;
        int c = n / 9, n9 = n % 9;
        int rr = n9 / 3, s = n9 % 3;
        out[posoff + c*32400 + rr*180 + s] = acc[rf][pf][r] * sc;
      }
    }
  }
}

extern "C" void kernel_launch(void* const* d_in, const int* in_sizes, int n_in,
                              void* d_out, int out_size, void* d_ws, size_t ws_size,
                              hipStream_t stream) {
  (void)in_sizes; (void)n_in; (void)out_size; (void)ws_size;
  const float* x   = (const float*)d_in[0];
  const float* Wa  = (const float*)d_in[1];
  const float* ba  = (const float*)d_in[2];
  const float* aa  = (const float*)d_in[3];
  const float* Wm1 = (const float*)d_in[4];
  const float* bm1 = (const float*)d_in[5];
  const float* am1 = (const float*)d_in[6];
  const float* Wm2 = (const float*)d_in[7];
  const float* bm2 = (const float*)d_in[8];
  const float* am2 = (const float*)d_in[9];
  float* out = (float*)d_out;

  float* E_t  = (float*)d_ws;
  float* xp   = E_t + SZ_E;
  float* refp = xp + SZ_XP;
  float* invn = refp + SZ_RP;
  float* y_t  = invn + SZ_IN;
  bf16_t* ApSwz = (bf16_t*)(y_t + SZ_Y);                 // 7,372,800 bf16
  bf16_t* EbSwz = ApSwz + (size_t)NB*45*16*5*64*8;       // 1,179,648 bf16

  hipMemsetAsync(d_ws, 0, (size_t)(SZ_E + SZ_XP + SZ_RP)*sizeof(float), stream);

  k_conv_embed<<<dim3(900, NB), 256, 0, stream>>>(x, Wa, ba, aa, E_t);
  k_conv_match<<<(NB*NC2*NPIX)/256, 256, 0, stream>>>(x, Wm1, bm1, am1, xp);
  k_conv_ref<<<(NB*NC2*HR*HR)/256, 256, 0, stream>>>(x, Wm2, bm2, am2, refp);
  k_invn<<<NB*NL, 64, 0, stream>>>(refp, invn);
  k_corr<<<dim3(8, 8, NB), 256, 0, stream>>>(xp, refp, y_t);
  k_softmax<<<(NB*NPIX)/4, 256, 0, stream>>>(y_t, invn);
  k_ebswz<<<dim3(576, NB), 256, 0, stream>>>(E_t, EbSwz);
  k_aprime<<<dim3(15, 15, NB), 256, 0, stream>>>(y_t, ApSwz);
  k_tgemm<<<dim3(45, 12, NB), 64, 0, stream>>>((const bf16x8*)EbSwz, (const bf16x8*)ApSwz, out);
}

// Round 4
// 265.827 us; speedup vs baseline: 4.9815x; 1.4442x over previous
//
#include <hip/hip_runtime.h>
#include <hip/hip_bf16.h>

typedef __hip_bfloat16 bf16_t;
using f32x4  = __attribute__((ext_vector_type(4))) float;
using bf16x8 = __attribute__((ext_vector_type(8))) short;

#define NB 4
#define NC 64
#define NC2 32
#define NH 60
#define NW 60
#define NPIX (NH*NW)         // 3600
#define HP 66                // embed padded (pad 3)
#define MP 62                // match padded (pad 1)
#define HR 20
#define RP 22                // ref padded (pad 1)
#define NL 400
#define OHW 180
#define KPAD 512

// workspace layout (floats)
#define SZ_E   (NB*HP*HP*NC)        // 1,115,136  E_t [b][row][col][c]
#define SZ_XP  (NB*NC2*MP*MP)       // 492,032    [b][c][62][62]
#define SZ_RP  (NB*NC2*RP*RP)       // 61,952     [b][c][22][22]
#define SZ_IN  (NB*NL)              // 1,600
#define SZ_Y   (NB*NPIX*NL)         // 5,760,000  y_t [b][h][w][l]
// then bf16: ApSwz 7,372,800 ; EbSwz 1,179,648 ; XpSwz 4,147,200 ; RfSwz 460,800

// embed conv1x1 + prelu -> padded, channel-fastest layout
__global__ __launch_bounds__(256) void k_conv_embed(
    const float* __restrict__ x, const float* __restrict__ Wa,
    const float* __restrict__ ba, const float* __restrict__ aa,
    float* __restrict__ E_t) {
  __shared__ float Ws[64*64];
  __shared__ float bs[64];
  __shared__ float al;
  int t = threadIdx.x;
  for (int i = t; i < 64*64; i += 256) {
    int co = i >> 6, c = i & 63;
    Ws[c*64 + co] = Wa[i];
  }
  if (t < 64) bs[t] = ba[t];
  if (t == 0) al = aa[0];
  __syncthreads();
  int lane = t & 63, wid = t >> 6;
  int pix = blockIdx.x * 4 + wid;
  int b = blockIdx.y;
  int ph = pix / NW, pw = pix % NW;
  const float* xb = x + b*NC*NPIX + pix;
  float acc = bs[lane];
  #pragma unroll 8
  for (int c = 0; c < 64; ++c)
    acc = fmaf(xb[c*NPIX], Ws[c*64 + lane], acc);
  acc = acc >= 0.f ? acc : al*acc;
  E_t[((b*HP + ph+3)*HP + (pw+3))*NC + lane] = acc;
}

// match conv1x1 + prelu -> padded [b][c2][62][62]
__global__ __launch_bounds__(256) void k_conv_match(
    const float* __restrict__ x, const float* __restrict__ Wm,
    const float* __restrict__ bm, const float* __restrict__ am,
    float* __restrict__ xp) {
  int idx = blockIdx.x*256 + threadIdx.x;
  if (idx >= NB*NC2*NPIX) return;
  int pix = idx % NPIX; int tmp = idx / NPIX;
  int co = tmp % NC2; int b = tmp / NC2;
  float alpha = am[0];
  const float* xb = x + b*NC*NPIX + pix;
  const float* wr = Wm + co*64;
  float acc = bm[co];
  #pragma unroll 8
  for (int c = 0; c < 64; ++c)
    acc = fmaf(xb[c*NPIX], wr[c], acc);
  acc = acc >= 0.f ? acc : alpha*acc;
  int ph = pix / NW, pw = pix % NW;
  xp[((b*NC2 + co)*MP + ph+1)*MP + (pw+1)] = acc;
}

// bilinear down (exact subsample at 3h+1) + conv1x1 + prelu -> padded [b][c2][22][22]
__global__ __launch_bounds__(256) void k_conv_ref(
    const float* __restrict__ x, const float* __restrict__ Wm,
    const float* __restrict__ bm, const float* __restrict__ am,
    float* __restrict__ refp) {
  int idx = blockIdx.x*256 + threadIdx.x;
  if (idx >= NB*NC2*HR*HR) return;
  int pos = idx % (HR*HR); int tmp = idx / (HR*HR);
  int co = tmp % NC2; int b = tmp / NC2;
  int hr = pos / HR, wr_ = pos % HR;
  float alpha = am[0];
  const float* xb = x + b*NC*NPIX + (3*hr+1)*NW + (3*wr_+1);
  const float* wrow = Wm + co*64;
  float acc = bm[co];
  #pragma unroll 8
  for (int c = 0; c < 64; ++c)
    acc = fmaf(xb[c*NPIX], wrow[c], acc);
  acc = acc >= 0.f ? acc : alpha*acc;
  refp[((b*NC2 + co)*RP + hr+1)*RP + (wr_+1)] = acc;
}

// per-(b,l) patch inverse norm
__global__ __launch_bounds__(64) void k_invn(
    const float* __restrict__ refp, float* __restrict__ invn) {
  int bl = blockIdx.x;
  int b = bl / NL, l = bl % NL;
  int lh = l / HR, lw = l % HR;
  int t = threadIdx.x;
  float ss = 0.f;
  for (int e = t; e < NC2*9; e += 64) {
    int c = e / 9, r = e % 9;
    int i = r / 3, j = r % 3;
    float v = refp[((b*NC2 + c)*RP + lh+i)*RP + (lw+j)];
    ss = fmaf(v, v, ss);
  }
  #pragma unroll
  for (int off = 32; off > 0; off >>= 1)
    ss += __shfl_xor(ss, off);
  if (t == 0) invn[bl] = 1.f / fmaxf(sqrtf(ss), 1e-4f);
}

// im2col(xp) -> A-fragment-swizzled bf16: [b][mblk(225)][ks(9)][slot(64)][8]
__global__ __launch_bounds__(256) void k_xpswz(
    const float* __restrict__ xp, bf16_t* __restrict__ Xp) {
  int tid = blockIdx.x*256 + threadIdx.x;   // 518,400 total
  int slot = tid & 63; int rest = tid >> 6;
  int ks = rest % 9; int rest2 = rest / 9;
  int mblk = rest2 % 225; int b = rest2 / 225;
  int m = mblk*16 + (slot & 15);
  int h = m / NW, w = m % NW;
  int k0 = ks*32 + (slot >> 4)*8;
  const float* xb = xp + (size_t)b*NC2*MP*MP;
  union { bf16_t a[8]; bf16x8 v; } u;
  #pragma unroll
  for (int j = 0; j < 8; ++j) {
    int k = k0 + j;
    int c = k / 9, r = k % 9;
    int i = r / 3, j2 = r % 3;
    u.a[j] = __float2bfloat16(xb[(c*MP + h + i)*MP + w + j2]);
  }
  *(bf16x8*)(Xp + (size_t)tid*8) = u.v;
}

// ref patches (pre-scaled by 10*invn) -> B-fragment-swizzled bf16: [b][nblk(25)][ks(9)][slot(64)][8]
__global__ __launch_bounds__(256) void k_rfswz(
    const float* __restrict__ refp, const float* __restrict__ invn,
    bf16_t* __restrict__ Rf) {
  int tid = blockIdx.x*256 + threadIdx.x;   // 57,600 total
  int slot = tid & 63; int rest = tid >> 6;
  int ks = rest % 9; int rest2 = rest / 9;
  int nblk = rest2 % 25; int b = rest2 / 25;
  int l = nblk*16 + (slot & 15);
  int lh = l / HR, lw = l % HR;
  float sc = 10.f * invn[b*NL + l];
  int k0 = ks*32 + (slot >> 4)*8;
  const float* rb = refp + (size_t)b*NC2*RP*RP;
  union { bf16_t a[8]; bf16x8 v; } u;
  #pragma unroll
  for (int j = 0; j < 8; ++j) {
    int k = k0 + j;
    int c = k / 9, r = k % 9;
    int i = r / 3, j2 = r % 3;
    u.a[j] = __float2bfloat16(rb[(c*RP + lh + i)*RP + lw + j2] * sc);
  }
  *(bf16x8*)(Rf + (size_t)tid*8) = u.v;
}

// correlation GEMM: y_t[b][m][l] = sum_k Xp[m][k]*Rf[l][k]  (logits, scale folded in)
// wave tile 48(m) x 80(l), K=288 (9 steps). grid (5, 75, NB), 1 wave/block.
__global__ __launch_bounds__(64) void k_cgemm(
    const bf16x8* __restrict__ Xp, const bf16x8* __restrict__ Rf,
    float* __restrict__ y_t) {
  int L = threadIdx.x;
  int nt = blockIdx.x, mt = blockIdx.y, b = blockIdx.z;
  const bf16x8* pa = Xp + ((size_t)(b*225 + mt*3)*9)*64 + L;  // +mf*576 +ks*64
  const bf16x8* pb = Rf + ((size_t)(b*25 + nt*5)*9)*64 + L;   // +nf*576 +ks*64
  f32x4 acc[3][5];
  #pragma unroll
  for (int i = 0; i < 3; ++i)
    #pragma unroll
    for (int j = 0; j < 5; ++j)
      acc[i][j] = {0.f, 0.f, 0.f, 0.f};
  bf16x8 af[3], bf[5], afn[3], bfn[5];
  #pragma unroll
  for (int i = 0; i < 3; ++i) af[i] = pa[i*576];
  #pragma unroll
  for (int j = 0; j < 5; ++j) bf[j] = pb[j*576];
  for (int ks = 0; ks < 9; ++ks) {
    if (ks < 8) {
      #pragma unroll
      for (int i = 0; i < 3; ++i) afn[i] = pa[i*576 + (ks+1)*64];
      #pragma unroll
      for (int j = 0; j < 5; ++j) bfn[j] = pb[j*576 + (ks+1)*64];
    }
    #pragma unroll
    for (int i = 0; i < 3; ++i)
      #pragma unroll
      for (int j = 0; j < 5; ++j)
        acc[i][j] = __builtin_amdgcn_mfma_f32_16x16x32_bf16(af[i], bf[j], acc[i][j], 0, 0, 0);
    #pragma unroll
    for (int i = 0; i < 3; ++i) af[i] = afn[i];
    #pragma unroll
    for (int j = 0; j < 5; ++j) bf[j] = bfn[j];
  }
  int quad = L >> 4, col = L & 15;
  #pragma unroll
  for (int mf = 0; mf < 3; ++mf) {
    #pragma unroll
    for (int r = 0; r < 4; ++r) {
      int m = mt*48 + mf*16 + quad*4 + r;
      float* row = y_t + ((size_t)(b*NPIX + m))*NL + nt*80 + col;
      #pragma unroll
      for (int nf = 0; nf < 5; ++nf)
        row[nf*16] = acc[mf][nf][r];
    }
  }
}

// softmax over L per (b,h,w); y_t already holds logits (10*invn folded in).
__global__ __launch_bounds__(256) void k_softmax(
    float* __restrict__ y_t) {
  int t = threadIdx.x;
  int lane = t & 63, wid = t >> 6;
  int gpos = blockIdx.x*4 + wid;
  int b = gpos / NPIX, rem = gpos % NPIX;
  float* yp = y_t + ((size_t)(b*NPIX + rem))*NL;
  float vals[7];
  float m = -1e30f;
  #pragma unroll
  for (int k = 0; k < 7; ++k) {
    int l = lane + 64*k;
    float v = -1e30f;
    if (l < NL) v = yp[l];
    vals[k] = v;
    m = fmaxf(m, v);
  }
  #pragma unroll
  for (int off = 32; off > 0; off >>= 1)
    m = fmaxf(m, __shfl_xor(m, off));
  float s = 0.f;
  #pragma unroll
  for (int k = 0; k < 7; ++k) {
    float e = expf(vals[k] - m);
    vals[k] = e;
    s += e;
  }
  #pragma unroll
  for (int off = 32; off > 0; off >>= 1)
    s += __shfl_xor(s, off);
  float r = 1.f / s;
  #pragma unroll
  for (int k = 0; k < 7; ++k) {
    int l = lane + 64*k;
    if (l < NL) yp[l] = vals[k] * r;
  }
}

// A'[b][m=(h0,w0)][k=(u,v)] = sum_{dh,dw} y[b,(u-dh,v-dw),h0+1-dh,w0+1-dw]
__global__ __launch_bounds__(256) void k_aprime(
    const float* __restrict__ y_t, bf16_t* __restrict__ Ap) {
  __shared__ float ys[36*NL];   // 57.6 KB
  int t = threadIdx.x;
  int b = blockIdx.z;
  int h0base = blockIdx.y*4, w0base = blockIdx.x*4;
  for (int idx = t; idx < 36*NL; idx += 256) {
    int pos = idx / NL, l = idx % NL;
    int i = pos / 6, jj = pos % 6;
    int hh = h0base - 1 + i, ww = w0base - 1 + jj;
    float v = 0.f;
    if (hh >= 0 && hh < NH && ww >= 0 && ww < NW)
      v = y_t[((size_t)(b*NPIX + hh*NW + ww))*NL + l];
    ys[idx] = v;
  }
  __syncthreads();
  int row = t >> 4, klane = t & 15;
  int h0r = row >> 2, w0r = row & 3;
  int m = (h0base + h0r)*NW + (w0base + w0r);
  int pblk = m / 80, pf = (m % 80) >> 4, mrow = m & 15;
  size_t rowbase = ((size_t)(b*45 + pblk)*16);
  for (int kk = 0; kk < 32; ++kk) {
    int k = klane + kk*16;
    float acc = 0.f;
    if (k < 484) {
      int u = k / 22, v = k % 22;
      #pragma unroll
      for (int dh = 0; dh < 3; ++dh) {
        #pragma unroll
        for (int dw = 0; dw < 3; ++dw) {
          int lh = u - dh, lw = v - dw;
          if ((unsigned)lh < HR && (unsigned)lw < HR) {
            int i = h0r + 2 - dh, jj = w0r + 2 - dw;
            acc += ys[(i*6 + jj)*NL + lh*HR + lw];
          }
        }
      }
    }
    size_t idx = (((rowbase + (k>>5))*5 + pf)*64 + ((k>>3)&3)*16 + mrow)*8 + (k&7);
    Ap[idx] = __float2bfloat16(acc);
  }
}

// Eb[b][n=(c,rr,s)][k=(u,v)] = E_pad[b][c][3u+rr][3v+s], A-frag swizzled
__global__ __launch_bounds__(256) void k_ebswz(
    const float* __restrict__ E_t, bf16_t* __restrict__ Eb) {
  int n = blockIdx.x, b = blockIdx.y;
  int c = n / 9, n9 = n % 9, rr = n9 / 3, s = n9 % 3;
  size_t nbase = ((size_t)(b*12 + n/48)*16);
  for (int k = threadIdx.x; k < KPAD; k += 256) {
    float v = 0.f;
    if (k < 484) {
      int u = k / 22, vv = k % 22;
      v = E_t[((size_t)((b*HP + 3*u + rr)*HP + 3*vv + s))*NC + c];
    }
    size_t idx = (((nbase + (k>>5))*3 + (n%48)/16)*64 + ((k>>3)&3)*16 + (n&15))*8 + (k&7);
    Eb[idx] = __float2bfloat16(v);
  }
}

// out GEMM: out[(c,rr,s)][(h0,w0)] = (1/6) sum_k Eb[n][k] * A'[m][k]
__global__ __launch_bounds__(64) void k_tgemm(
    const bf16x8* __restrict__ Eb, const bf16x8* __restrict__ Ap,
    float* __restrict__ out) {
  int L = threadIdx.x;
  int pb = blockIdx.x, rb = blockIdx.y, b = blockIdx.z;
  const bf16x8* pa = Eb + ((size_t)(b*12 + rb)*16)*3*64 + L;
  const bf16x8* pp = Ap + ((size_t)(b*45 + pb)*16)*5*64 + L;
  f32x4 acc[3][5];
  #pragma unroll
  for (int i = 0; i < 3; ++i)
    #pragma unroll
    for (int j = 0; j < 5; ++j)
      acc[i][j] = {0.f, 0.f, 0.f, 0.f};
  bf16x8 af[3], bf[5], afn[3], bfn[5];
  #pragma unroll
  for (int i = 0; i < 3; ++i) af[i] = pa[i*64];
  #pragma unroll
  for (int j = 0; j < 5; ++j) bf[j] = pp[j*64];
  for (int ks = 0; ks < 16; ++ks) {
    if (ks < 15) {
      const bf16x8* na = pa + (ks+1)*192;
      const bf16x8* nb = pp + (ks+1)*320;
      #pragma unroll
      for (int i = 0; i < 3; ++i) afn[i] = na[i*64];
      #pragma unroll
      for (int j = 0; j < 5; ++j) bfn[j] = nb[j*64];
    }
    #pragma unroll
    for (int i = 0; i < 3; ++i)
      #pragma unroll
      for (int j = 0; j < 5; ++j)
        acc[i][j] = __builtin_amdgcn_mfma_f32_16x16x32_bf16(af[i], bf[j], acc[i][j], 0, 0, 0);
    #pragma unroll
    for (int i = 0; i < 3; ++i) af[i] = afn[i];
    #pragma unroll
    for (int j = 0; j < 5; ++j) bf[j] = bfn[j];
  }
  int quad = L >> 4, col = L & 15;
  const float sc = 1.f/6.f;
  #pragma unroll
  for (int pf = 0; pf < 5; ++pf) {
    int m = pb*80 + pf*16 + col;
    int h0 = m / 60, w0 = m % 60;
    int posoff = b*(NC*OHW*OHW) + h0*540 + w0*3;
    #pragma unroll
    for (int rf = 0; rf < 3; ++rf) {
      #pragma unroll
      for (int r = 0; r < 4; ++r) {
        int n = rb*48 + rf*16 + quad*4 + r;
        int c = n / 9, n9 = n % 9;
        int rr = n9 / 3, s = n9 % 3;
        out[posoff + c*32400 + rr*180 + s] = acc[rf][pf][r] * sc;
      }
    }
  }
}

extern "C" void kernel_launch(void* const* d_in, const int* in_sizes, int n_in,
                              void* d_out, int out_size, void* d_ws, size_t ws_size,
                              hipStream_t stream) {
  (void)in_sizes; (void)n_in; (void)out_size; (void)ws_size;
  const float* x   = (const float*)d_in[0];
  const float* Wa  = (const float*)d_in[1];
  const float* ba  = (const float*)d_in[2];
  const float* aa  = (const float*)d_in[3];
  const float* Wm1 = (const float*)d_in[4];
  const float* bm1 = (const float*)d_in[5];
  const float* am1 = (const float*)d_in[6];
  const float* Wm2 = (const float*)d_in[7];
  const float* bm2 = (const float*)d_in[8];
  const float* am2 = (const float*)d_in[9];
  float* out = (float*)d_out;

  float* E_t  = (float*)d_ws;
  float* xp   = E_t + SZ_E;
  float* refp = xp + SZ_XP;
  float* invn = refp + SZ_RP;
  float* y_t  = invn + SZ_IN;
  bf16_t* ApSwz = (bf16_t*)(y_t + SZ_Y);                 // 7,372,800 bf16
  bf16_t* EbSwz = ApSwz + (size_t)NB*45*16*5*64*8;       // 1,179,648 bf16
  bf16_t* XpSwz = EbSwz + (size_t)NB*12*16*3*64*8;       // 4,147,200 bf16
  bf16_t* RfSwz = XpSwz + (size_t)NB*225*9*64*8;         //   460,800 bf16

  hipMemsetAsync(d_ws, 0, (size_t)(SZ_E + SZ_XP + SZ_RP)*sizeof(float), stream);

  k_conv_embed<<<dim3(900, NB), 256, 0, stream>>>(x, Wa, ba, aa, E_t);
  k_conv_match<<<(NB*NC2*NPIX)/256, 256, 0, stream>>>(x, Wm1, bm1, am1, xp);
  k_conv_ref<<<(NB*NC2*HR*HR)/256, 256, 0, stream>>>(x, Wm2, bm2, am2, refp);
  k_invn<<<NB*NL, 64, 0, stream>>>(refp, invn);
  k_xpswz<<<2025, 256, 0, stream>>>(xp, XpSwz);
  k_rfswz<<<225, 256, 0, stream>>>(refp, invn, RfSwz);
  k_cgemm<<<dim3(5, 75, NB), 64, 0, stream>>>((const bf16x8*)XpSwz, (const bf16x8*)RfSwz, y_t);
  k_softmax<<<(NB*NPIX)/4, 256, 0, stream>>>(y_t);
  k_ebswz<<<dim3(576, NB), 256, 0, stream>>>(E_t, EbSwz);
  k_aprime<<<dim3(15, 15, NB), 256, 0, stream>>>(y_t, ApSwz);
  k_tgemm<<<dim3(45, 12, NB), 64, 0, stream>>>((const bf16x8*)EbSwz, (const bf16x8*)ApSwz, out);
}

// Round 5
// 222.354 us; speedup vs baseline: 5.9554x; 1.1955x over previous
//
#include <hip/hip_runtime.h>
#include <hip/hip_bf16.h>

typedef __hip_bfloat16 bf16_t;
using f32x4  = __attribute__((ext_vector_type(4))) float;
using bf16x8 = __attribute__((ext_vector_type(8))) short;

#define NB 4
#define NC 64
#define NC2 32
#define NH 60
#define NW 60
#define NPIX (NH*NW)         // 3600
#define HP 66                // embed padded (pad 3)
#define MP 62                // match padded (pad 1)
#define HR 20
#define RP 22                // ref padded (pad 1)
#define NL 400
#define OHW 180
#define KPAD 512

// workspace layout (floats)
#define SZ_E   (NB*HP*HP*NC)        // 1,115,136  E_t [b][row][col][c]
#define SZ_XP  (NB*NC2*MP*MP)       // 492,032    [b][c][62][62]
#define SZ_RP  (NB*NC2*RP*RP)       // 61,952     [b][c][22][22]
#define SZ_IN  (NB*NL)              // 1,600
#define SZ_Y   (NB*NPIX*NL)         // 5,760,000  y_t [b][h][w][l]
// then bf16: ApSwz 7,372,800 ; EbSwz 1,179,648 ; XpSwz 4,147,200 ; RfSwz 460,800

// embed conv1x1 + prelu -> padded, channel-fastest layout
__global__ __launch_bounds__(256) void k_conv_embed(
    const float* __restrict__ x, const float* __restrict__ Wa,
    const float* __restrict__ ba, const float* __restrict__ aa,
    float* __restrict__ E_t) {
  __shared__ float Ws[64*64];
  __shared__ float bs[64];
  __shared__ float al;
  int t = threadIdx.x;
  for (int i = t; i < 64*64; i += 256) {
    int co = i >> 6, c = i & 63;
    Ws[c*64 + co] = Wa[i];
  }
  if (t < 64) bs[t] = ba[t];
  if (t == 0) al = aa[0];
  __syncthreads();
  int lane = t & 63, wid = t >> 6;
  int pix = blockIdx.x * 4 + wid;
  int b = blockIdx.y;
  int ph = pix / NW, pw = pix % NW;
  const float* xb = x + b*NC*NPIX + pix;
  float acc = bs[lane];
  #pragma unroll 8
  for (int c = 0; c < 64; ++c)
    acc = fmaf(xb[c*NPIX], Ws[c*64 + lane], acc);
  acc = acc >= 0.f ? acc : al*acc;
  E_t[((b*HP + ph+3)*HP + (pw+3))*NC + lane] = acc;
}

// match conv1x1 + prelu -> padded [b][c2][62][62]
__global__ __launch_bounds__(256) void k_conv_match(
    const float* __restrict__ x, const float* __restrict__ Wm,
    const float* __restrict__ bm, const float* __restrict__ am,
    float* __restrict__ xp) {
  int idx = blockIdx.x*256 + threadIdx.x;
  if (idx >= NB*NC2*NPIX) return;
  int pix = idx % NPIX; int tmp = idx / NPIX;
  int co = tmp % NC2; int b = tmp / NC2;
  float alpha = am[0];
  const float* xb = x + b*NC*NPIX + pix;
  const float* wr = Wm + co*64;
  float acc = bm[co];
  #pragma unroll 8
  for (int c = 0; c < 64; ++c)
    acc = fmaf(xb[c*NPIX], wr[c], acc);
  acc = acc >= 0.f ? acc : alpha*acc;
  int ph = pix / NW, pw = pix % NW;
  xp[((b*NC2 + co)*MP + ph+1)*MP + (pw+1)] = acc;
}

// bilinear down (exact subsample at 3h+1) + conv1x1 + prelu -> padded [b][c2][22][22]
__global__ __launch_bounds__(256) void k_conv_ref(
    const float* __restrict__ x, const float* __restrict__ Wm,
    const float* __restrict__ bm, const float* __restrict__ am,
    float* __restrict__ refp) {
  int idx = blockIdx.x*256 + threadIdx.x;
  if (idx >= NB*NC2*HR*HR) return;
  int pos = idx % (HR*HR); int tmp = idx / (HR*HR);
  int co = tmp % NC2; int b = tmp / NC2;
  int hr = pos / HR, wr_ = pos % HR;
  float alpha = am[0];
  const float* xb = x + b*NC*NPIX + (3*hr+1)*NW + (3*wr_+1);
  const float* wrow = Wm + co*64;
  float acc = bm[co];
  #pragma unroll 8
  for (int c = 0; c < 64; ++c)
    acc = fmaf(xb[c*NPIX], wrow[c], acc);
  acc = acc >= 0.f ? acc : alpha*acc;
  refp[((b*NC2 + co)*RP + hr+1)*RP + (wr_+1)] = acc;
}

// per-(b,l) patch inverse norm
__global__ __launch_bounds__(64) void k_invn(
    const float* __restrict__ refp, float* __restrict__ invn) {
  int bl = blockIdx.x;
  int b = bl / NL, l = bl % NL;
  int lh = l / HR, lw = l % HR;
  int t = threadIdx.x;
  float ss = 0.f;
  for (int e = t; e < NC2*9; e += 64) {
    int c = e / 9, r = e % 9;
    int i = r / 3, j = r % 3;
    float v = refp[((b*NC2 + c)*RP + lh+i)*RP + (lw+j)];
    ss = fmaf(v, v, ss);
  }
  #pragma unroll
  for (int off = 32; off > 0; off >>= 1)
    ss += __shfl_xor(ss, off);
  if (t == 0) invn[bl] = 1.f / fmaxf(sqrtf(ss), 1e-4f);
}

// im2col(xp) -> A-fragment-swizzled bf16: [b][mblk(225)][ks(9)][slot(64)][8]
__global__ __launch_bounds__(256) void k_xpswz(
    const float* __restrict__ xp, bf16_t* __restrict__ Xp) {
  int tid = blockIdx.x*256 + threadIdx.x;   // 518,400 total
  int slot = tid & 63; int rest = tid >> 6;
  int ks = rest % 9; int rest2 = rest / 9;
  int mblk = rest2 % 225; int b = rest2 / 225;
  int m = mblk*16 + (slot & 15);
  int h = m / NW, w = m % NW;
  int k0 = ks*32 + (slot >> 4)*8;
  const float* xb = xp + (size_t)b*NC2*MP*MP;
  union { bf16_t a[8]; bf16x8 v; } u;
  #pragma unroll
  for (int j = 0; j < 8; ++j) {
    int k = k0 + j;
    int c = k / 9, r = k % 9;
    int i = r / 3, j2 = r % 3;
    u.a[j] = __float2bfloat16(xb[(c*MP + h + i)*MP + w + j2]);
  }
  *(bf16x8*)(Xp + (size_t)tid*8) = u.v;
}

// ref patches (pre-scaled by 10*invn) -> B-fragment-swizzled bf16: [b][nblk(25)][ks(9)][slot(64)][8]
__global__ __launch_bounds__(256) void k_rfswz(
    const float* __restrict__ refp, const float* __restrict__ invn,
    bf16_t* __restrict__ Rf) {
  int tid = blockIdx.x*256 + threadIdx.x;   // 57,600 total
  int slot = tid & 63; int rest = tid >> 6;
  int ks = rest % 9; int rest2 = rest / 9;
  int nblk = rest2 % 25; int b = rest2 / 25;
  int l = nblk*16 + (slot & 15);
  int lh = l / HR, lw = l % HR;
  float sc = 10.f * invn[b*NL + l];
  int k0 = ks*32 + (slot >> 4)*8;
  const float* rb = refp + (size_t)b*NC2*RP*RP;
  union { bf16_t a[8]; bf16x8 v; } u;
  #pragma unroll
  for (int j = 0; j < 8; ++j) {
    int k = k0 + j;
    int c = k / 9, r = k % 9;
    int i = r / 3, j2 = r % 3;
    u.a[j] = __float2bfloat16(rb[(c*RP + lh + i)*RP + lw + j2] * sc);
  }
  *(bf16x8*)(Rf + (size_t)tid*8) = u.v;
}

// correlation GEMM: y_t[b][m][l] = sum_k Xp[m][k]*Rf[l][k]
__global__ __launch_bounds__(64) void k_cgemm(
    const bf16x8* __restrict__ Xp, const bf16x8* __restrict__ Rf,
    float* __restrict__ y_t) {
  int L = threadIdx.x;
  int nt = blockIdx.x, mt = blockIdx.y, b = blockIdx.z;
  const bf16x8* pa = Xp + ((size_t)(b*225 + mt*3)*9)*64 + L;
  const bf16x8* pb = Rf + ((size_t)(b*25 + nt*5)*9)*64 + L;
  f32x4 acc[3][5];
  #pragma unroll
  for (int i = 0; i < 3; ++i)
    #pragma unroll
    for (int j = 0; j < 5; ++j)
      acc[i][j] = {0.f, 0.f, 0.f, 0.f};
  bf16x8 af[3], bf[5], afn[3], bfn[5];
  #pragma unroll
  for (int i = 0; i < 3; ++i) af[i] = pa[i*576];
  #pragma unroll
  for (int j = 0; j < 5; ++j) bf[j] = pb[j*576];
  for (int ks = 0; ks < 9; ++ks) {
    if (ks < 8) {
      #pragma unroll
      for (int i = 0; i < 3; ++i) afn[i] = pa[i*576 + (ks+1)*64];
      #pragma unroll
      for (int j = 0; j < 5; ++j) bfn[j] = pb[j*576 + (ks+1)*64];
    }
    #pragma unroll
    for (int i = 0; i < 3; ++i)
      #pragma unroll
      for (int j = 0; j < 5; ++j)
        acc[i][j] = __builtin_amdgcn_mfma_f32_16x16x32_bf16(af[i], bf[j], acc[i][j], 0, 0, 0);
    #pragma unroll
    for (int i = 0; i < 3; ++i) af[i] = afn[i];
    #pragma unroll
    for (int j = 0; j < 5; ++j) bf[j] = bfn[j];
  }
  int quad = L >> 4, col = L & 15;
  #pragma unroll
  for (int mf = 0; mf < 3; ++mf) {
    #pragma unroll
    for (int r = 0; r < 4; ++r) {
      int m = mt*48 + mf*16 + quad*4 + r;
      float* row = y_t + ((size_t)(b*NPIX + m))*NL + nt*80 + col;
      #pragma unroll
      for (int nf = 0; nf < 5; ++nf)
        row[nf*16] = acc[mf][nf][r];
    }
  }
}

// softmax over L per (b,h,w); y_t holds logits (scale folded in).
__global__ __launch_bounds__(256) void k_softmax(
    float* __restrict__ y_t) {
  int t = threadIdx.x;
  int lane = t & 63, wid = t >> 6;
  int gpos = blockIdx.x*4 + wid;
  int b = gpos / NPIX, rem = gpos % NPIX;
  float* yp = y_t + ((size_t)(b*NPIX + rem))*NL;
  float vals[7];
  float m = -1e30f;
  #pragma unroll
  for (int k = 0; k < 7; ++k) {
    int l = lane + 64*k;
    float v = -1e30f;
    if (l < NL) v = yp[l];
    vals[k] = v;
    m = fmaxf(m, v);
  }
  #pragma unroll
  for (int off = 32; off > 0; off >>= 1)
    m = fmaxf(m, __shfl_xor(m, off));
  float s = 0.f;
  #pragma unroll
  for (int k = 0; k < 7; ++k) {
    float e = expf(vals[k] - m);
    vals[k] = e;
    s += e;
  }
  #pragma unroll
  for (int off = 32; off > 0; off >>= 1)
    s += __shfl_xor(s, off);
  float r = 1.f / s;
  #pragma unroll
  for (int k = 0; k < 7; ++k) {
    int l = lane + 64*k;
    if (l < NL) yp[l] = vals[k] * r;
  }
}

// A'[b][m=(h0,w0)][k=(u,v)] = sum_{dh,dw} y[b,(u-dh,v-dw),h0+1-dh,w0+1-dw]
// 2x4 position tile/block; zero-padded bf16 LDS window [24 slots][24x24];
// 9-term sum = 9 ds_read_u16 at constant offsets (no bounds checks).
__global__ __launch_bounds__(256) void k_aprime(
    const float* __restrict__ y_t, bf16_t* __restrict__ Ap) {
  __shared__ uint4 raw[1728];                 // 27648 B
  unsigned short* ysp = (unsigned short*)raw;
  int t = threadIdx.x;
  int b = blockIdx.z;
  int h0base = blockIdx.y*2, w0base = blockIdx.x*4;   // grid (15,30,NB)
  for (int i = t; i < 1728; i += 256) raw[i] = uint4{0,0,0,0};
  __syncthreads();
  // stage 24 halo positions x 400 l (as float2 -> packed bf16x2)
  for (int idx = t; idx < 4800; idx += 256) {
    int pos = idx / 200, l2 = idx % 200;
    int i = pos / 6, jj = pos % 6;
    int hh = h0base - 1 + i, ww = w0base - 1 + jj;
    if ((unsigned)hh < NH && (unsigned)ww < NW) {
      const float* src = y_t + ((size_t)(b*NPIX + hh*NW + ww))*NL + 2*l2;
      float v0 = src[0], v1 = src[1];
      int l = 2*l2, lh = l / HR, lw = l % HR;
      union { bf16_t h[2]; unsigned int u; } pk;
      pk.h[0] = __float2bfloat16(v0);
      pk.h[1] = __float2bfloat16(v1);
      // element offset even -> 4B aligned
      *(unsigned int*)&ysp[pos*576 + (lh+2)*24 + (lw+2)] = pk.u;
    }
  }
  __syncthreads();
  int row = t >> 5;                 // 0..7
  int klane = t & 31;
  int h0r = row >> 2, w0r = row & 3;
  int m = (h0base + h0r)*NW + (w0base + w0r);
  int pblk = m / 80, pf = (m % 80) >> 4, mrow = m & 15;
  size_t rowbase = ((size_t)(b*45 + pblk)*16);
  const unsigned short* basep = ysp + (h0r*6 + w0r)*576;
  for (int kk = 0; kk < 16; ++kk) {
    int k = kk*32 + klane;
    float acc = 0.f;
    if (k < 484) {
      int u = k / 22, v = k - 22*u;
      const unsigned short* q = basep + u*24 + v;
      #pragma unroll
      for (int dh = 0; dh < 3; ++dh) {
        #pragma unroll
        for (int dw = 0; dw < 3; ++dw) {
          unsigned short rbits = q[dh*3480 + dw*577];
          acc += __uint_as_float(((unsigned int)rbits) << 16);
        }
      }
    }
    size_t idx = (((rowbase + (k>>5))*5 + pf)*64 + ((k>>3)&3)*16 + mrow)*8 + (k&7);
    Ap[idx] = __float2bfloat16(acc);
  }
}

// Eb[b][n=(c,rr,s)][k=(u,v)] = E_pad[b][c][3u+rr][3v+s], A-frag swizzled
__global__ __launch_bounds__(256) void k_ebswz(
    const float* __restrict__ E_t, bf16_t* __restrict__ Eb) {
  int n = blockIdx.x, b = blockIdx.y;
  int c = n / 9, n9 = n % 9, rr = n9 / 3, s = n9 % 3;
  size_t nbase = ((size_t)(b*12 + n/48)*16);
  for (int k = threadIdx.x; k < KPAD; k += 256) {
    float v = 0.f;
    if (k < 484) {
      int u = k / 22, vv = k % 22;
      v = E_t[((size_t)((b*HP + 3*u + rr)*HP + 3*vv + s))*NC + c];
    }
    size_t idx = (((nbase + (k>>5))*3 + (n%48)/16)*64 + ((k>>3)&3)*16 + (n&15))*8 + (k&7);
    Eb[idx] = __float2bfloat16(v);
  }
}

// out GEMM: out[(c,rr,s)][(h0,w0)] = (1/6) sum_k Eb[n][k] * A'[m][k]
__global__ __launch_bounds__(64) void k_tgemm(
    const bf16x8* __restrict__ Eb, const bf16x8* __restrict__ Ap,
    float* __restrict__ out) {
  int L = threadIdx.x;
  int pb = blockIdx.x, rb = blockIdx.y, b = blockIdx.z;
  const bf16x8* pa = Eb + ((size_t)(b*12 + rb)*16)*3*64 + L;
  const bf16x8* pp = Ap + ((size_t)(b*45 + pb)*16)*5*64 + L;
  f32x4 acc[3][5];
  #pragma unroll
  for (int i = 0; i < 3; ++i)
    #pragma unroll
    for (int j = 0; j < 5; ++j)
      acc[i][j] = {0.f, 0.f, 0.f, 0.f};
  bf16x8 af[3], bf[5], afn[3], bfn[5];
  #pragma unroll
  for (int i = 0; i < 3; ++i) af[i] = pa[i*64];
  #pragma unroll
  for (int j = 0; j < 5; ++j) bf[j] = pp[j*64];
  for (int ks = 0; ks < 16; ++ks) {
    if (ks < 15) {
      const bf16x8* na = pa + (ks+1)*192;
      const bf16x8* nb = pp + (ks+1)*320;
      #pragma unroll
      for (int i = 0; i < 3; ++i) afn[i] = na[i*64];
      #pragma unroll
      for (int j = 0; j < 5; ++j) bfn[j] = nb[j*64];
    }
    #pragma unroll
    for (int i = 0; i < 3; ++i)
      #pragma unroll
      for (int j = 0; j < 5; ++j)
        acc[i][j] = __builtin_amdgcn_mfma_f32_16x16x32_bf16(af[i], bf[j], acc[i][j], 0, 0, 0);
    #pragma unroll
    for (int i = 0; i < 3; ++i) af[i] = afn[i];
    #pragma unroll
    for (int j = 0; j < 5; ++j) bf[j] = bfn[j];
  }
  int quad = L >> 4, col = L & 15;
  const float sc = 1.f/6.f;
  #pragma unroll
  for (int pf = 0; pf < 5; ++pf) {
    int m = pb*80 + pf*16 + col;
    int h0 = m / 60, w0 = m % 60;
    int posoff = b*(NC*OHW*OHW) + h0*540 + w0*3;
    #pragma unroll
    for (int rf = 0; rf < 3; ++rf) {
      #pragma unroll
      for (int r = 0; r < 4; ++r) {
        int n = rb*48 + rf*16 + quad*4 + r;
        int c = n / 9, n9 = n % 9;
        int rr = n9 / 3, s = n9 % 3;
        out[posoff + c*32400 + rr*180 + s] = acc[rf][pf][r] * sc;
      }
    }
  }
}

extern "C" void kernel_launch(void* const* d_in, const int* in_sizes, int n_in,
                              void* d_out, int out_size, void* d_ws, size_t ws_size,
                              hipStream_t stream) {
  (void)in_sizes; (void)n_in; (void)out_size; (void)ws_size;
  const float* x   = (const float*)d_in[0];
  const float* Wa  = (const float*)d_in[1];
  const float* ba  = (const float*)d_in[2];
  const float* aa  = (const float*)d_in[3];
  const float* Wm1 = (const float*)d_in[4];
  const float* bm1 = (const float*)d_in[5];
  const float* am1 = (const float*)d_in[6];
  const float* Wm2 = (const float*)d_in[7];
  const float* bm2 = (const float*)d_in[8];
  const float* am2 = (const float*)d_in[9];
  float* out = (float*)d_out;

  float* E_t  = (float*)d_ws;
  float* xp   = E_t + SZ_E;
  float* refp = xp + SZ_XP;
  float* invn = refp + SZ_RP;
  float* y_t  = invn + SZ_IN;
  bf16_t* ApSwz = (bf16_t*)(y_t + SZ_Y);                 // 7,372,800 bf16
  bf16_t* EbSwz = ApSwz + (size_t)NB*45*16*5*64*8;       // 1,179,648 bf16
  bf16_t* XpSwz = EbSwz + (size_t)NB*12*16*3*64*8;       // 4,147,200 bf16
  bf16_t* RfSwz = XpSwz + (size_t)NB*225*9*64*8;         //   460,800 bf16

  hipMemsetAsync(d_ws, 0, (size_t)(SZ_E + SZ_XP + SZ_RP)*sizeof(float), stream);

  k_conv_embed<<<dim3(900, NB), 256, 0, stream>>>(x, Wa, ba, aa, E_t);
  k_conv_match<<<(NB*NC2*NPIX)/256, 256, 0, stream>>>(x, Wm1, bm1, am1, xp);
  k_conv_ref<<<(NB*NC2*HR*HR)/256, 256, 0, stream>>>(x, Wm2, bm2, am2, refp);
  k_invn<<<NB*NL, 64, 0, stream>>>(refp, invn);
  k_xpswz<<<2025, 256, 0, stream>>>(xp, XpSwz);
  k_rfswz<<<225, 256, 0, stream>>>(refp, invn, RfSwz);
  k_cgemm<<<dim3(5, 75, NB), 64, 0, stream>>>((const bf16x8*)XpSwz, (const bf16x8*)RfSwz, y_t);
  k_softmax<<<(NB*NPIX)/4, 256, 0, stream>>>(y_t);
  k_ebswz<<<dim3(576, NB), 256, 0, stream>>>(E_t, EbSwz);
  k_aprime<<<dim3(15, 30, NB), 256, 0, stream>>>(y_t, ApSwz);
  k_tgemm<<<dim3(45, 12, NB), 64, 0, stream>>>((const bf16x8*)EbSwz, (const bf16x8*)ApSwz, out);
}